// Round 3
// baseline (385.129 us; speedup 1.0000x reference)
//
#include <hip/hip_runtime.h>
#include <math.h>

#define NN 512
#define KP 64
#define NPANEL 8
#define NTHR 256
#define NBLK 256

// Exp-domain soft Floyd-Warshall:
//   E = exp(-w/gamma); step k: E += outer(E[:,k], E[k,:])   (rank-1, Jacobi)
// One plain launch per K=64 panel phase (inter-launch barrier = phase sync):
//   blocks 0..15 : build panel-p snapshots (C_p, R_p). E holds state p-1 in
//                  cross(p); add C_{p-1}R_{p-1} on the fly, write corrected
//                  slices back to E. Evolve diag block (64 serial Jacobi
//                  steps, redundant per block), forward-substitute snapshots.
//   blocks 16..255: apply C_{p-1}R_{p-1} to complement(cross(p)) (p>0),
//                  or initialize E there (p==0).
// Diag block (p,p) is never written in phase p; diag b misses exactly
// C_{b-1}R_{b-1}, fixed in the final loss pass, which also adds C_7R_7.
// All contributions >= 0 -> reassociation-safe vs the reference recurrence.

__global__ __launch_bounds__(NTHR) void fw_phase(
    const float* __restrict__ s, const float* __restrict__ dI,
    float* __restrict__ E, float* __restrict__ Cs, float* __restrict__ Rs,
    int p) {
  const int blk = blockIdx.x, tid = threadIdx.x;
  const int k0 = p * KP;

  __shared__ float Ds[KP][KP + 1];                 // corrected diag (state p)
  __shared__ float Sl[KP][KP + 1];                 // corrected slice / staging
  __shared__ __align__(16) float Ut[KP][KP];       // R-tile, then history
  __shared__ float rowbuf[2][KP];
  __shared__ float colbuf[2][KP];                  // [c*16+i] = D[c+4i][m]

  if (blk >= 16) {
    // ================= trailing blocks =================
    const int gt = (blk - 16) * NTHR + tid;
    if (gt >= 448 * 112) return;
    const int ii = gt / 112;
    const int jj = gt - ii * 112;
    const int i = (ii < k0) ? ii : ii + KP;
    const int j = ((jj < (p << 4)) ? jj : jj + 16) << 2;
    const int idx = i * NN + j;
    if (p == 0) {
      // init complement of cross(0): E = exp(-10 * w0)
      const float4 sv = *(const float4*)(s + idx);
      const float4 dv = *(const float4*)(dI + idx);
      float w0 = dv.x / (sv.x + 1e-4f); if (i == j + 0) w0 = 0.f;
      float w1 = dv.y / (sv.y + 1e-4f); if (i == j + 1) w1 = 0.f;
      float w2 = dv.z / (sv.z + 1e-4f); if (i == j + 2) w2 = 0.f;
      float w3 = dv.w / (sv.w + 1e-4f); if (i == j + 3) w3 = 0.f;
      *(float4*)(E + idx) = make_float4(expf(-10.f * w0), expf(-10.f * w1),
                                        expf(-10.f * w2), expf(-10.f * w3));
    } else {
      const float* Cprev = Cs + (size_t)(p - 1) * (NN * KP);
      const float* Rprev = Rs + (size_t)(p - 1) * (KP * NN);
      float4 acc = *(const float4*)(E + idx);
      const float* crow = Cprev + (size_t)i * KP;
      const float* rcol = Rprev + j;
#pragma unroll 8
      for (int r = 0; r < KP; ++r) {
        const float cv = crow[r];
        const float4 rv = *(const float4*)(rcol + (size_t)r * NN);
        acc.x += cv * rv.x; acc.y += cv * rv.y;
        acc.z += cv * rv.z; acc.w += cv * rv.w;
      }
      *(float4*)(E + idx) = acc;
    }
    return;
  }

  // ================= panel blocks =================
  const bool isC = (blk < 8);
  const int sb = isC ? blk : (blk - 8);
  const int sOff = sb * KP;
  const bool haveSl = (sb != p);   // slice distinct from diag block?
  const int r0 = (tid >> 4) << 2;  // 4x4 register tile for corrections
  const int m0 = (tid & 15) << 2;

  if (p == 0) {
    // direct init of diag + own slice from s,d; write cross(0) to E
    for (int e = tid; e < KP * KP; e += NTHR) {
      const int a = e >> 6, b = e & 63;
      float w = dI[a * NN + b] / (s[a * NN + b] + 1e-4f);
      if (a == b) w = 0.f;
      const float v = expf(-10.f * w);
      Ds[a][b] = v;
      if (blk == 0) E[a * NN + b] = v;         // single writer for diag
      if (haveSl) {
        const int gi = isC ? (sOff + a) : a;
        const int gj = isC ? b : (sOff + b);   // gi != gj guaranteed
        const float w2 = dI[gi * NN + gj] / (s[gi * NN + gj] + 1e-4f);
        const float v2 = expf(-10.f * w2);
        Sl[a][b] = v2;
        E[gi * NN + gj] = v2;
      }
    }
    __syncthreads();
  } else {
    const float* Cprev = Cs + (size_t)(p - 1) * (NN * KP);
    const float* Rprev = Rs + (size_t)(p - 1) * (KP * NN);
    // stage C-tile(rows k0) -> Sl, R-tile(cols k0) -> Ut
    for (int e = tid; e < KP * KP; e += NTHR) {
      const int a = e >> 6, b = e & 63;
      Sl[a][b] = Cprev[(size_t)(k0 + a) * KP + b];
      Ut[a][b] = Rprev[(size_t)a * NN + (k0 + b)];
    }
    __syncthreads();
    // Ds = E[diag] + Ctile * Rtile   (state p)
    float acc[4][4];
#pragma unroll
    for (int i2 = 0; i2 < 4; ++i2) {
      const float4 ev = *(const float4*)(E + (size_t)(k0 + r0 + i2) * NN + (k0 + m0));
      acc[i2][0] = ev.x; acc[i2][1] = ev.y; acc[i2][2] = ev.z; acc[i2][3] = ev.w;
    }
    for (int rr = 0; rr < KP; ++rr) {
      const float4 b4 = *(const float4*)(&Ut[rr][m0]);
#pragma unroll
      for (int i2 = 0; i2 < 4; ++i2) {
        const float av = Sl[r0 + i2][rr];
        acc[i2][0] += av * b4.x; acc[i2][1] += av * b4.y;
        acc[i2][2] += av * b4.z; acc[i2][3] += av * b4.w;
      }
    }
#pragma unroll
    for (int i2 = 0; i2 < 4; ++i2)
#pragma unroll
      for (int j2 = 0; j2 < 4; ++j2) Ds[r0 + i2][m0 + j2] = acc[i2][j2];
    __syncthreads();   // Ds done; all tile reads done

    if (haveSl) {
      // swap in the differing tile; correct own slice to state p
      if (isC) {
        for (int e = tid; e < KP * KP; e += NTHR) {
          const int a = e >> 6, b = e & 63;
          Sl[a][b] = Cprev[(size_t)(sOff + a) * KP + b];   // C rows sOff
        }
      } else {
        for (int e = tid; e < KP * KP; e += NTHR) {
          const int a = e >> 6, b = e & 63;
          Ut[a][b] = Rprev[(size_t)a * NN + (sOff + b)];   // R cols sOff
        }
      }
      __syncthreads();
      const int bi0 = isC ? (sOff + r0) : (k0 + r0);
      const int bj0 = isC ? (k0 + m0) : (sOff + m0);
#pragma unroll
      for (int i2 = 0; i2 < 4; ++i2) {
        const float4 ev = *(const float4*)(E + (size_t)(bi0 + i2) * NN + bj0);
        acc[i2][0] = ev.x; acc[i2][1] = ev.y; acc[i2][2] = ev.z; acc[i2][3] = ev.w;
      }
      for (int rr = 0; rr < KP; ++rr) {
        const float4 b4 = *(const float4*)(&Ut[rr][m0]);
#pragma unroll
        for (int i2 = 0; i2 < 4; ++i2) {
          const float av = Sl[r0 + i2][rr];
          acc[i2][0] += av * b4.x; acc[i2][1] += av * b4.y;
          acc[i2][2] += av * b4.z; acc[i2][3] += av * b4.w;
        }
      }
      __syncthreads();   // tile reads done before Sl is overwritten
#pragma unroll
      for (int i2 = 0; i2 < 4; ++i2) {
#pragma unroll
        for (int j2 = 0; j2 < 4; ++j2) Sl[r0 + i2][m0 + j2] = acc[i2][j2];
        // write corrected slice (state p) back to E — unique writer region
        *(float4*)(E + (size_t)(bi0 + i2) * NN + bj0) =
            make_float4(acc[i2][0], acc[i2][1], acc[i2][2], acc[i2][3]);
      }
      __syncthreads();   // Sl ready for substitution
    }
  }

  // ---- evolve diag block: 64 serial rank-1 Jacobi steps ----
  const int t = tid & 63;
  const int c = tid >> 6;
  float dreg[16];
#pragma unroll
  for (int i2 = 0; i2 < 16; ++i2) dreg[i2] = Ds[c + 4 * i2][t];
#pragma unroll
  for (int m = 0; m < KP; ++m) {
    const int q = m & 1;
    if (c == (m & 3)) rowbuf[q][t] = dreg[m >> 2];
    if (t == m) {
#pragma unroll
      for (int i2 = 0; i2 < 16; ++i2) colbuf[q][c * 16 + i2] = dreg[i2];
    }
    __syncthreads();
    if (tid < KP)   // snapshot history (Ut's tile role is dead by now)
      Ut[m][tid] = isC ? rowbuf[q][tid]
                       : colbuf[q][((tid & 3) << 4) | (tid >> 2)];
    const float rm = rowbuf[q][t];
#pragma unroll
    for (int i2 = 0; i2 < 16; ++i2) dreg[i2] += colbuf[q][c * 16 + i2] * rm;
  }
  __syncthreads();

  // ---- forward substitution -> snapshot panels ----
  if (tid < KP) {
    float v[KP];
    if (isC) {
#pragma unroll
      for (int m = 0; m < KP; ++m) v[m] = haveSl ? Sl[tid][m] : Ds[tid][m];
    } else {
#pragma unroll
      for (int m = 0; m < KP; ++m) v[m] = haveSl ? Sl[m][tid] : Ds[m][tid];
    }
#pragma unroll
    for (int mp = 0; mp < KP - 1; ++mp) {
      const float vmp = v[mp];
#pragma unroll
      for (int m = mp + 1; m < KP; ++m) v[m] += vmp * Ut[mp][m];
    }
    if (isC) {
#pragma unroll
      for (int m = 0; m < KP; ++m) Sl[tid][m] = v[m];
    } else {
#pragma unroll
      for (int m = 0; m < KP; ++m) Sl[m][tid] = v[m];
    }
  }
  __syncthreads();
  float* Cp = Cs + (size_t)p * (NN * KP);
  float* Rp = Rs + (size_t)p * (KP * NN);
  if (isC) {
    for (int e = tid; e < KP * KP; e += NTHR) {
      const int a = e >> 6, b = e & 63;
      Cp[(size_t)(sOff + a) * KP + b] = Sl[a][b];
    }
  } else {
    for (int e = tid; e < KP * KP; e += NTHR) {
      const int a = e >> 6, b = e & 63;
      Rp[(size_t)a * NN + (sOff + b)] = Sl[a][b];
    }
  }
}

__device__ __forceinline__ float loss_elem(float Ev, float sv, float ov,
                                           float dv, float fv, int i, int j,
                                           float esc) {
  const float sp = (Ev > 0.f) ? (-0.1f * logf(Ev)) : 1e9f;
  const float ur = expf(-0.005f * sp);
  const float ub = expf(-0.01f * dv);
  const float choice = ur / (ur + ub);
  const float ug = fv * choice * (dv - 0.5f * sp);
  const float util = (ug > 0.f) ? (ug + 1.f) : expf(ug);  // elu + 1
  const float ent = sv * (((i == j) ? 1.f : 0.f) - sv);
  return sv * dv + util + esc * ent * ent + 10000.f * (sv * (1.f - ov));
}

// Final pass: E + C7*R7 (+ diag fixup C_{b-1}R_{b-1}) -> fused loss reduce.
__global__ __launch_bounds__(NTHR) void k_loss(
    const float* __restrict__ s, const float* __restrict__ o,
    const float* __restrict__ dI, const float* __restrict__ f,
    const int* __restrict__ ep, const float* __restrict__ E,
    const float* __restrict__ Cs, const float* __restrict__ Rs,
    float* __restrict__ out) {
  __shared__ float red[NTHR];
  const int tid = threadIdx.x;
  const int g = blockIdx.x * NTHR + tid;
  const int idx0 = g * 4;
  const int i = idx0 >> 9;
  const int j = idx0 & (NN - 1);
  const float* C7 = Cs + (size_t)7 * (NN * KP);
  const float* R7 = Rs + (size_t)7 * (KP * NN);
  float4 acc = *(const float4*)(E + idx0);
  {
    const float* crow = C7 + (size_t)i * KP;
    const float* rcol = R7 + j;
#pragma unroll 8
    for (int r = 0; r < KP; ++r) {
      const float cv = crow[r];
      const float4 rv = *(const float4*)(rcol + (size_t)r * NN);
      acc.x += cv * rv.x; acc.y += cv * rv.y;
      acc.z += cv * rv.z; acc.w += cv * rv.w;
    }
  }
  const int bi = i >> 6, bj = j >> 6;
  if (bi == bj && bi >= 1) {   // diag block: add the skipped C_{b-1}R_{b-1}
    const float* cf = Cs + (size_t)(bi - 1) * (NN * KP) + (size_t)i * KP;
    const float* rf = Rs + (size_t)(bi - 1) * (KP * NN) + j;
#pragma unroll 8
    for (int r = 0; r < KP; ++r) {
      const float cv = cf[r];
      const float4 rv = *(const float4*)(rf + (size_t)r * NN);
      acc.x += cv * rv.x; acc.y += cv * rv.y;
      acc.z += cv * rv.z; acc.w += cv * rv.w;
    }
  }
  const float4 sv = *(const float4*)(s + idx0);
  const float4 ov = *(const float4*)(o + idx0);
  const float4 dv = *(const float4*)(dI + idx0);
  const float4 fv = *(const float4*)(f + idx0);
  const int e = ep[0];
  const float esc = (e < 0) ? 0.f : (e < 10) ? 0.05f : (e < 50) ? 0.1f : 1.f;
  float lsum = loss_elem(acc.x, sv.x, ov.x, dv.x, fv.x, i, j + 0, esc)
             + loss_elem(acc.y, sv.y, ov.y, dv.y, fv.y, i, j + 1, esc)
             + loss_elem(acc.z, sv.z, ov.z, dv.z, fv.z, i, j + 2, esc)
             + loss_elem(acc.w, sv.w, ov.w, dv.w, fv.w, i, j + 3, esc);
  red[tid] = lsum;
  __syncthreads();
#pragma unroll
  for (int st = 128; st > 0; st >>= 1) {
    if (tid < st) red[tid] += red[tid + st];
    __syncthreads();
  }
  if (tid == 0) atomicAdd(out, red[0]);
}

extern "C" void kernel_launch(void* const* d_in, const int* in_sizes, int n_in,
                              void* d_out, int out_size, void* d_ws, size_t ws_size,
                              hipStream_t stream) {
  const float* s = (const float*)d_in[0];   // soft_adj
  const float* o = (const float*)d_in[1];   // original_adj
  const float* d = (const float*)d_in[2];   // distances
  const float* f = (const float*)d_in[3];   // flow
  const int* ep = (const int*)d_in[4];      // epoch

  float* E = (float*)d_ws;                  // 512*512
  float* Cs = E + NN * NN;                  // 8 x [512*64]
  float* Rs = Cs + NPANEL * NN * KP;        // 8 x [64*512]
  float* out = (float*)d_out;

  hipMemsetAsync(d_out, 0, sizeof(float), stream);
  for (int p = 0; p < NPANEL; ++p)
    fw_phase<<<NBLK, NTHR, 0, stream>>>(s, d, E, Cs, Rs, p);
  k_loss<<<NBLK, NTHR, 0, stream>>>(s, o, d, f, ep, E, Cs, Rs, out);
}

// Round 4
// 336.136 us; speedup vs baseline: 1.1458x; 1.1458x over previous
//
#include <hip/hip_runtime.h>
#include <math.h>

#define NN 512
#define KP 64
#define NPANEL 8
#define NTHR 256
#define NBLK 256

// LDS layout (floats). V_ holds the diag block (early) then the V-state for
// substitution (stride 65). B2_ stages C-tiles (stride 65). UT_ (stride 64,
// 16B-aligned rows) stages R-tiles, then the evolve snapshot history.
#define V_   0
#define B2_  4160
#define UT_  8320
#define RB_  12416
#define CB_  12544
#define LDSN 12672

__device__ __forceinline__ float einit(const float* s, const float* dI, int i, int j) {
  float w = dI[i * NN + j] / (s[i * NN + j] + 1e-4f);
  if (i == j) w = 0.f;
  return expf(-10.f * w);
}

// Phase p (one launch each; inter-launch barrier = phase sync):
//  blocks 0..31 : panel blocks (2 per slice; blk<16 C-side, else R-side).
//    Correct cross slices with C_{p-1}R_{p-1} (E holds state p-1 there),
//    write corrected (state p) back to E; evolve diag 64 Jacobi steps
//    (redundant per block) capturing snapshot history; chunked forward
//    substitution -> snapshot panels C_p, R_p.
//  blocks 32..255: apply C_{p-1}R_{p-1} to complement(cross(p)) (p>0) or
//    initialize E there (p==0). Diag blocks never written in-phase; diag b
//    misses exactly C_{b-1}R_{b-1}, fixed in k_loss (which also adds C_7R_7).
__global__ __launch_bounds__(NTHR) void fw_phase(
    const float* __restrict__ s, const float* __restrict__ dI,
    float* __restrict__ E, float* __restrict__ Cs, float* __restrict__ Rs,
    float* __restrict__ out, int p) {
  __shared__ __align__(16) float lds[LDSN];
  const int blk = blockIdx.x, tid = threadIdx.x;
  const int k0 = p * KP;

  if (blk >= 32) {
    // ================= trailing blocks =================
    const int gt = (blk - 32) * NTHR + tid;
    if (p == 0) {
      if (blk == 32 && tid == 0) out[0] = 0.f;   // zero accumulator for k_loss
      if (gt < 448 * 112) {
        const int ii = gt / 112;
        const int jj = gt - ii * 112;
        const int i = ii + KP;                    // k0 == 0
        const int j = ((jj < 0) ? jj : jj + 16) << 2;
        const int idx = i * NN + j;
        const float4 sv = *(const float4*)(s + idx);
        const float4 dv = *(const float4*)(dI + idx);
        float w0 = dv.x / (sv.x + 1e-4f); if (i == j + 0) w0 = 0.f;
        float w1 = dv.y / (sv.y + 1e-4f); if (i == j + 1) w1 = 0.f;
        float w2 = dv.z / (sv.z + 1e-4f); if (i == j + 2) w2 = 0.f;
        float w3 = dv.w / (sv.w + 1e-4f); if (i == j + 3) w3 = 0.f;
        *(float4*)(E + idx) = make_float4(expf(-10.f * w0), expf(-10.f * w1),
                                          expf(-10.f * w2), expf(-10.f * w3));
      }
    } else if (gt < 448 * 112) {
      const int ii = gt / 112;
      const int jj = gt - ii * 112;
      const int i = (ii < k0) ? ii : ii + KP;
      const int j = ((jj < (p << 4)) ? jj : jj + 16) << 2;
      const int idx = i * NN + j;
      const float* Cprev = Cs + (size_t)(p - 1) * (NN * KP);
      const float* Rprev = Rs + (size_t)(p - 1) * (KP * NN);
      float4 acc = *(const float4*)(E + idx);
      const float* crow = Cprev + (size_t)i * KP;
      const float* rcol = Rprev + j;
#pragma unroll 8
      for (int r = 0; r < KP; ++r) {
        const float cv = crow[r];
        const float4 rv = *(const float4*)(rcol + (size_t)r * NN);
        acc.x += cv * rv.x; acc.y += cv * rv.y;
        acc.z += cv * rv.z; acc.w += cv * rv.w;
      }
      *(float4*)(E + idx) = acc;
    }
    return;
  }

  // ================= panel blocks =================
  const bool isC = (blk < 16);
  const int sb = (blk >> 1) & 7;
  const int h = blk & 1;                 // half: rows/cols [32h, 32h+32)
  const int sOff = sb * KP;
  const bool haveSl = (sb != p);
  const float* Cprev = Cs + (size_t)(p - 1) * (NN * KP);
  const float* Rprev = Rs + (size_t)(p - 1) * (KP * NN);

  if (p > 0) {
    // stage B2 = C-tile rows k0, UT = R-tile cols k0
    for (int e = tid; e < KP * KP; e += NTHR) {
      const int a = e >> 6, b = e & 63;
      lds[B2_ + a * 65 + b] = Cprev[(size_t)(k0 + a) * KP + b];
      lds[UT_ + a * 64 + b] = Rprev[(size_t)a * NN + (k0 + b)];
    }
    __syncthreads();
    // diag GEMM: V(=Ds) = E[diag] + B2*UT (state p), 4x4 per thread
    {
      const int r0 = (tid >> 4) << 2, m0 = (tid & 15) << 2;
      float acc[4][4];
#pragma unroll
      for (int i2 = 0; i2 < 4; ++i2) {
        const float4 ev = *(const float4*)(E + (size_t)(k0 + r0 + i2) * NN + (k0 + m0));
        acc[i2][0] = ev.x; acc[i2][1] = ev.y; acc[i2][2] = ev.z; acc[i2][3] = ev.w;
      }
      for (int rr = 0; rr < KP; ++rr) {
        const float4 b4 = *(const float4*)&lds[UT_ + rr * 64 + m0];
#pragma unroll
        for (int i2 = 0; i2 < 4; ++i2) {
          const float av = lds[B2_ + (r0 + i2) * 65 + rr];
          acc[i2][0] += av * b4.x; acc[i2][1] += av * b4.y;
          acc[i2][2] += av * b4.z; acc[i2][3] += av * b4.w;
        }
      }
#pragma unroll
      for (int i2 = 0; i2 < 4; ++i2)
#pragma unroll
        for (int j2 = 0; j2 < 4; ++j2)
          lds[V_ + (r0 + i2) * 65 + (m0 + j2)] = acc[i2][j2];
    }
    __syncthreads();
  } else {
    // p == 0: fill V with diag init; blk 0 also writes E diag
    for (int e = tid; e < KP * KP; e += NTHR) {
      const int a = e >> 6, b = e & 63;
      const float v = einit(s, dI, a, b);
      lds[V_ + a * 65 + b] = v;
      if (blk == 0) E[a * NN + b] = v;
    }
    __syncthreads();
  }

  // load evolve register tile from corrected diag (before V overwrites it)
  const int t = tid & 63, c = tid >> 6;
  float dreg[16];
#pragma unroll
  for (int i2 = 0; i2 < 16; ++i2) dreg[i2] = lds[V_ + (c + 4 * i2) * 65 + t];
  __syncthreads();

  // -------- build V-state (corrected C0/R0, row-major in the solve dim) ----
  if (p > 0) {
    if (haveSl) {
      if (isC) {
        for (int e = tid; e < KP * KP; e += NTHR) {
          const int a = e >> 6, b = e & 63;
          lds[B2_ + a * 65 + b] = Cprev[(size_t)(sOff + a) * KP + b];
        }
      } else {
        for (int e = tid; e < KP * KP; e += NTHR) {
          const int a = e >> 6, b = e & 63;
          lds[UT_ + a * 64 + b] = Rprev[(size_t)a * NN + (sOff + b)];
        }
      }
      __syncthreads();
      if (tid < 128) {
        float acc[4][4];
        if (isC) {
          const int r0 = 32 * h + ((tid >> 4) << 2);   // slice row band
          const int m0 = (tid & 15) << 2;              // m 0..63
#pragma unroll
          for (int i2 = 0; i2 < 4; ++i2) {
            const float4 ev = *(const float4*)(E + (size_t)(sOff + r0 + i2) * NN + (k0 + m0));
            acc[i2][0] = ev.x; acc[i2][1] = ev.y; acc[i2][2] = ev.z; acc[i2][3] = ev.w;
          }
          for (int rr = 0; rr < KP; ++rr) {
            const float4 b4 = *(const float4*)&lds[UT_ + rr * 64 + m0];
#pragma unroll
            for (int i2 = 0; i2 < 4; ++i2) {
              const float av = lds[B2_ + (r0 + i2) * 65 + rr];
              acc[i2][0] += av * b4.x; acc[i2][1] += av * b4.y;
              acc[i2][2] += av * b4.z; acc[i2][3] += av * b4.w;
            }
          }
#pragma unroll
          for (int i2 = 0; i2 < 4; ++i2) {
            *(float4*)(E + (size_t)(sOff + r0 + i2) * NN + (k0 + m0)) =
                make_float4(acc[i2][0], acc[i2][1], acc[i2][2], acc[i2][3]);
#pragma unroll
            for (int j2 = 0; j2 < 4; ++j2)
              lds[V_ + (r0 + i2) * 65 + (m0 + j2)] = acc[i2][j2];
          }
        } else {
          const int r0 = (tid & 15) << 2;              // m rows 0..63
          const int c0 = 32 * h + ((tid >> 4) << 2);   // slice col band
#pragma unroll
          for (int i2 = 0; i2 < 4; ++i2) {
            const float4 ev = *(const float4*)(E + (size_t)(k0 + r0 + i2) * NN + (sOff + c0));
            acc[i2][0] = ev.x; acc[i2][1] = ev.y; acc[i2][2] = ev.z; acc[i2][3] = ev.w;
          }
          for (int rr = 0; rr < KP; ++rr) {
            const float4 b4 = *(const float4*)&lds[UT_ + rr * 64 + c0];
#pragma unroll
            for (int i2 = 0; i2 < 4; ++i2) {
              const float av = lds[B2_ + (r0 + i2) * 65 + rr];
              acc[i2][0] += av * b4.x; acc[i2][1] += av * b4.y;
              acc[i2][2] += av * b4.z; acc[i2][3] += av * b4.w;
            }
          }
#pragma unroll
          for (int i2 = 0; i2 < 4; ++i2) {
            *(float4*)(E + (size_t)(k0 + r0 + i2) * NN + (sOff + c0)) =
                make_float4(acc[i2][0], acc[i2][1], acc[i2][2], acc[i2][3]);
#pragma unroll
            for (int j2 = 0; j2 < 4; ++j2)
              lds[V_ + (c0 + j2) * 65 + (r0 + i2)] = acc[i2][j2];   // V[j][m]
          }
        }
      }
      __syncthreads();
    } else if (!isC) {
      // diag slice, R-side: V[j][m] = Ds[m][j] (in-place transpose)
      float tr[16];
#pragma unroll
      for (int u = 0; u < 16; ++u) {
        const int e = tid + u * NTHR;
        tr[u] = lds[V_ + (e >> 6) * 65 + (e & 63)];
      }
      __syncthreads();
#pragma unroll
      for (int u = 0; u < 16; ++u) {
        const int e = tid + u * NTHR;
        lds[V_ + (e & 63) * 65 + (e >> 6)] = tr[u];
      }
      __syncthreads();
    }
  } else {
    if (haveSl) {
      if (isC) {
        for (int e = tid; e < 2048; e += NTHR) {
          const int a = 32 * h + (e >> 6), b = e & 63;
          const float v = einit(s, dI, sOff + a, b);
          lds[V_ + a * 65 + b] = v;
          E[(sOff + a) * NN + b] = v;
        }
      } else {
        for (int e = tid; e < 2048; e += NTHR) {
          const int m = e >> 5, j = 32 * h + (e & 31);
          const float v = einit(s, dI, m, sOff + j);
          lds[V_ + j * 65 + m] = v;
          E[m * NN + (sOff + j)] = v;
        }
      }
      __syncthreads();
    } else if (!isC) {
      float tr[16];
#pragma unroll
      for (int u = 0; u < 16; ++u) {
        const int e = tid + u * NTHR;
        tr[u] = lds[V_ + (e >> 6) * 65 + (e & 63)];
      }
      __syncthreads();
#pragma unroll
      for (int u = 0; u < 16; ++u) {
        const int e = tid + u * NTHR;
        lds[V_ + (e & 63) * 65 + (e >> 6)] = tr[u];
      }
      __syncthreads();
    }
  }

  // -------- evolve diag: 64 serial rank-1 Jacobi steps, capture history ----
#pragma unroll
  for (int m = 0; m < KP; ++m) {
    const int q = m & 1;
    if (c == (m & 3)) lds[RB_ + q * 64 + t] = dreg[m >> 2];
    if (t == m) {
#pragma unroll
      for (int i2 = 0; i2 < 16; ++i2) lds[CB_ + q * 64 + c * 16 + i2] = dreg[i2];
    }
    __syncthreads();
    if (tid < KP)
      lds[UT_ + m * 64 + tid] =
          isC ? lds[RB_ + q * 64 + tid]
              : lds[CB_ + q * 64 + (((tid & 3) << 4) | (tid >> 2))];
    const float rm = lds[RB_ + q * 64 + t];
#pragma unroll
    for (int u = 0; u < 4; ++u) {
      const float4 cb = *(const float4*)&lds[CB_ + q * 64 + c * 16 + 4 * u];
      dreg[4 * u + 0] += cb.x * rm; dreg[4 * u + 1] += cb.y * rm;
      dreg[4 * u + 2] += cb.z * rm; dreg[4 * u + 3] += cb.w * rm;
    }
  }
  __syncthreads();

  // -------- chunked forward substitution on V rows [32h, 32h+32) ----------
  for (int cch = 0; cch < 4; ++cch) {
    const int mb = cch * 16;
    if (cch > 0 && tid < 128) {
      const int r = 32 * h + (tid & 31);
      const int g = tid >> 5;                    // 0..3
      const int m0c = mb + 4 * g;
      const int vb = V_ + r * 65;
      float a0 = lds[vb + m0c + 0], a1 = lds[vb + m0c + 1];
      float a2 = lds[vb + m0c + 2], a3 = lds[vb + m0c + 3];
      for (int mp = 0; mp < mb; ++mp) {
        const float vr = lds[vb + mp];
        const float4 u4 = *(const float4*)&lds[UT_ + mp * 64 + m0c];
        a0 += vr * u4.x; a1 += vr * u4.y; a2 += vr * u4.z; a3 += vr * u4.w;
      }
      lds[vb + m0c + 0] = a0; lds[vb + m0c + 1] = a1;
      lds[vb + m0c + 2] = a2; lds[vb + m0c + 3] = a3;
    }
    __syncthreads();
    if (tid < 32) {
      const int r = 32 * h + tid;
      const int vb = V_ + r * 65 + mb;
      float v[16];
#pragma unroll
      for (int u2 = 0; u2 < 16; ++u2) v[u2] = lds[vb + u2];
#pragma unroll
      for (int mp = 0; mp < 15; ++mp) {
        const float vmp = v[mp];
#pragma unroll
        for (int m2 = mp + 1; m2 < 16; ++m2)
          v[m2] += vmp * lds[UT_ + (mb + mp) * 64 + (mb + m2)];
      }
#pragma unroll
      for (int u2 = 0; u2 < 16; ++u2) lds[vb + u2] = v[u2];
    }
    __syncthreads();
  }

  // -------- snapshot panel writeout --------
  float* Cp = Cs + (size_t)p * (NN * KP);
  float* Rp = Rs + (size_t)p * (KP * NN);
  if (isC) {
    for (int e = tid; e < 2048; e += NTHR) {
      const int a = 32 * h + (e >> 6), b = e & 63;
      Cp[(size_t)(sOff + a) * KP + b] = lds[V_ + a * 65 + b];
    }
  } else {
    for (int e = tid; e < 2048; e += NTHR) {
      const int m = e >> 5, j = 32 * h + (e & 31);
      Rp[(size_t)m * NN + (sOff + j)] = lds[V_ + j * 65 + m];
    }
  }
}

__device__ __forceinline__ float loss_elem(float Ev, float sv, float ov,
                                           float dv, float fv, int i, int j,
                                           float esc) {
  const float sp = (Ev > 0.f) ? (-0.1f * logf(Ev)) : 1e9f;
  const float ur = expf(-0.005f * sp);
  const float ub = expf(-0.01f * dv);
  const float choice = ur / (ur + ub);
  const float ug = fv * choice * (dv - 0.5f * sp);
  const float util = (ug > 0.f) ? (ug + 1.f) : expf(ug);  // elu + 1
  const float ent = sv * (((i == j) ? 1.f : 0.f) - sv);
  return sv * dv + util + esc * ent * ent + 10000.f * (sv * (1.f - ov));
}

// Final pass: E + C7*R7 (+ diag fixup C_{b-1}R_{b-1}) -> fused loss reduce.
__global__ __launch_bounds__(NTHR) void k_loss(
    const float* __restrict__ s, const float* __restrict__ o,
    const float* __restrict__ dI, const float* __restrict__ f,
    const int* __restrict__ ep, const float* __restrict__ E,
    const float* __restrict__ Cs, const float* __restrict__ Rs,
    float* __restrict__ out) {
  __shared__ float red[NTHR];
  const int tid = threadIdx.x;
  const int g = blockIdx.x * NTHR + tid;
  const int idx0 = g * 4;
  const int i = idx0 >> 9;
  const int j = idx0 & (NN - 1);
  const float* C7 = Cs + (size_t)7 * (NN * KP);
  const float* R7 = Rs + (size_t)7 * (KP * NN);
  float4 acc = *(const float4*)(E + idx0);
  {
    const float* crow = C7 + (size_t)i * KP;
    const float* rcol = R7 + j;
#pragma unroll 8
    for (int r = 0; r < KP; ++r) {
      const float cv = crow[r];
      const float4 rv = *(const float4*)(rcol + (size_t)r * NN);
      acc.x += cv * rv.x; acc.y += cv * rv.y;
      acc.z += cv * rv.z; acc.w += cv * rv.w;
    }
  }
  const int bi = i >> 6, bj = j >> 6;
  if (bi == bj && bi >= 1) {
    const float* cf = Cs + (size_t)(bi - 1) * (NN * KP) + (size_t)i * KP;
    const float* rf = Rs + (size_t)(bi - 1) * (KP * NN) + j;
#pragma unroll 8
    for (int r = 0; r < KP; ++r) {
      const float cv = cf[r];
      const float4 rv = *(const float4*)(rf + (size_t)r * NN);
      acc.x += cv * rv.x; acc.y += cv * rv.y;
      acc.z += cv * rv.z; acc.w += cv * rv.w;
    }
  }
  const float4 sv = *(const float4*)(s + idx0);
  const float4 ov = *(const float4*)(o + idx0);
  const float4 dv = *(const float4*)(dI + idx0);
  const float4 fv = *(const float4*)(f + idx0);
  const int e = ep[0];
  const float esc = (e < 0) ? 0.f : (e < 10) ? 0.05f : (e < 50) ? 0.1f : 1.f;
  float lsum = loss_elem(acc.x, sv.x, ov.x, dv.x, fv.x, i, j + 0, esc)
             + loss_elem(acc.y, sv.y, ov.y, dv.y, fv.y, i, j + 1, esc)
             + loss_elem(acc.z, sv.z, ov.z, dv.z, fv.z, i, j + 2, esc)
             + loss_elem(acc.w, sv.w, ov.w, dv.w, fv.w, i, j + 3, esc);
  red[tid] = lsum;
  __syncthreads();
#pragma unroll
  for (int st = 128; st > 0; st >>= 1) {
    if (tid < st) red[tid] += red[tid + st];
    __syncthreads();
  }
  if (tid == 0) atomicAdd(out, red[0]);
}

extern "C" void kernel_launch(void* const* d_in, const int* in_sizes, int n_in,
                              void* d_out, int out_size, void* d_ws, size_t ws_size,
                              hipStream_t stream) {
  const float* s = (const float*)d_in[0];   // soft_adj
  const float* o = (const float*)d_in[1];   // original_adj
  const float* d = (const float*)d_in[2];   // distances
  const float* f = (const float*)d_in[3];   // flow
  const int* ep = (const int*)d_in[4];      // epoch

  float* E = (float*)d_ws;                  // 512*512
  float* Cs = E + NN * NN;                  // 8 x [512*64]
  float* Rs = Cs + NPANEL * NN * KP;        // 8 x [64*512]
  float* out = (float*)d_out;

  for (int p = 0; p < NPANEL; ++p)
    fw_phase<<<NBLK, NTHR, 0, stream>>>(s, d, E, Cs, Rs, out, p);
  k_loss<<<NBLK, NTHR, 0, stream>>>(s, o, d, f, ep, E, Cs, Rs, out);
}